// Round 4
// baseline (1413.052 us; speedup 1.0000x reference)
//
#include <hip/hip_runtime.h>
#include <cstdint>

typedef __bf16 bf16x8 __attribute__((ext_vector_type(8)));
typedef short s16x4 __attribute__((ext_vector_type(4)));
typedef float f32x4 __attribute__((ext_vector_type(4)));
typedef unsigned short ushort_t;

constexpr int kS  = 2048;
constexpr int kDM = 2048;
constexpr int kDK = 128;
constexpr int kNH = 16;
constexpr int kB  = 2;
constexpr int kNQKV = kDM + 2 * kDK;   // 2304 fused QKV output columns

__device__ __forceinline__ unsigned short f2bf(float f) {
  union { float f; unsigned u; } v; v.f = f;
  unsigned u = v.u;
  u += 0x7fffu + ((u >> 16) & 1u);
  return (unsigned short)(u >> 16);
}

// async global->LDS, 16B per lane (dest = wave-uniform base + lane*16)
__device__ __forceinline__ void gload16(const void* g, void* l) {
  __builtin_amdgcn_global_load_lds(
      (const __attribute__((address_space(1))) void*)g,
      (__attribute__((address_space(3))) void*)l, 16, 0, 0);
}

// ---------------- fp32 -> bf16 cast ----------------
__global__ __launch_bounds__(256) void cast_f32_bf16(const float* __restrict__ in,
                                                     ushort_t* __restrict__ out, long n) {
  long i = ((long)blockIdx.x * 256 + threadIdx.x) * 4;
  if (i >= n) return;
  float4 f = *reinterpret_cast<const float4*>(in + i);
  ushort4 o;
  o.x = f2bf(f.x); o.y = f2bf(f.y); o.z = f2bf(f.z); o.w = f2bf(f.w);
  *reinterpret_cast<ushort4*>(out + i) = o;
}

// ---------------- transpose + cast: fp32 [R x C] -> bf16 [C x R] ----------------
__global__ __launch_bounds__(256) void transpose_cast(const float* __restrict__ in,
                                                      ushort_t* __restrict__ out,
                                                      int R, int C) {
  __shared__ float tile[32][33];
  int c = blockIdx.x * 32 + threadIdx.x;
  int r0 = blockIdx.y * 32;
  #pragma unroll
  for (int i = threadIdx.y; i < 32; i += 8)
    tile[i][threadIdx.x] = in[(long)(r0 + i) * C + c];
  __syncthreads();
  int oc  = r0 + threadIdx.x;
  int or0 = blockIdx.x * 32;
  #pragma unroll
  for (int i = threadIdx.y; i < 32; i += 8)
    out[(long)(or0 + i) * R + oc] = f2bf(tile[threadIdx.x][i]);
}

// ---------------- 128x128 GEMM core (R1 structure: row-major LDS, 64B-contig staging) ----
__device__ __forceinline__ void gemm128(const ushort_t* __restrict__ A, int lda,
                                        const ushort_t* __restrict__ Bt, int ldb,
                                        int K, int row0, int col0,
                                        f32x4 (&acc)[4][4]) {
  __shared__ __align__(16) ushort_t sA[128 * 32];
  __shared__ __align__(16) ushort_t sB[128 * 32];
  int t = threadIdx.x;
  int r = t >> 2, c4 = t & 3;
  const ushort_t* gA0 = A  + (long)(row0 + r)      * lda + c4 * 8;
  const ushort_t* gA1 = A  + (long)(row0 + r + 64) * lda + c4 * 8;
  const ushort_t* gB0 = Bt + (long)(col0 + r)      * ldb + c4 * 8;
  const ushort_t* gB1 = Bt + (long)(col0 + r + 64) * ldb + c4 * 8;
  int lane = t & 63, wave = t >> 6;
  int wr = wave >> 1, wc = wave & 1;
  int lr = lane & 15, lg = lane >> 4;
  int aoff = (wr * 64 + lr) * 32 + lg * 8;
  int boff = (wc * 64 + lr) * 32 + lg * 8;

  for (int kk = 0; kk < K; kk += 32) {
    gload16(gA0 + kk, (void*)(sA + t * 8));
    gload16(gA1 + kk, (void*)(sA + 2048 + t * 8));
    gload16(gB0 + kk, (void*)(sB + t * 8));
    gload16(gB1 + kk, (void*)(sB + 2048 + t * 8));
    __syncthreads();
    bf16x8 af[4], bg[4];
    #pragma unroll
    for (int i = 0; i < 4; i++) af[i] = *(const bf16x8*)(sA + aoff + i * 16 * 32);
    #pragma unroll
    for (int j = 0; j < 4; j++) bg[j] = *(const bf16x8*)(sB + boff + j * 16 * 32);
    #pragma unroll
    for (int i = 0; i < 4; i++)
      #pragma unroll
      for (int j = 0; j < 4; j++)
        acc[i][j] = __builtin_amdgcn_mfma_f32_16x16x32_bf16(af[i], bg[j], acc[i][j], 0, 0, 0);
    __syncthreads();
  }
}

// fused QKV projection (+ fused V^T production)
__global__ __launch_bounds__(256) void gemm_qkv(const ushort_t* __restrict__ x,
    const ushort_t* __restrict__ Wt, const float* __restrict__ bq,
    const float* __restrict__ bk, const float* __restrict__ bv,
    ushort_t* __restrict__ Qb, float* __restrict__ Kc,
    ushort_t* __restrict__ Kb, float* __restrict__ Vc, ushort_t* __restrict__ Vtb) {
  f32x4 acc[4][4] = {};
  int row0 = blockIdx.y * 128, col0 = blockIdx.x * 128;
  gemm128(x, kDM, Wt, kDM, kDM, row0, col0, acc);
  int lane = threadIdx.x & 63, wave = threadIdx.x >> 6;
  int wr = wave >> 1, wc = wave & 1, lr = lane & 15, lg = lane >> 4;
  #pragma unroll
  for (int i = 0; i < 4; i++) {
    #pragma unroll
    for (int j = 0; j < 4; j++) {
      int col = col0 + wc * 64 + j * 16 + lr;
      float bias = (col < kDM) ? bq[col]
                 : (col < kDM + kDK) ? bk[col - kDM] : bv[col - kDM - kDK];
      #pragma unroll
      for (int rr = 0; rr < 4; rr++) {
        int row = row0 + wr * 64 + i * 16 + lg * 4 + rr;
        float v = acc[i][j][rr] + bias;
        if (col < kDM) {
          Qb[(long)row * kDM + col] = f2bf(v);
        } else if (col < kDM + kDK) {
          int c = col - kDM;
          Kc[(long)row * kDK + c] = v;
          Kb[(long)row * kDK + c] = f2bf(v);
        } else {
          int c = col - kDM - kDK;
          Vc[(long)row * kDK + c] = v;
          Vtb[((long)(row >> 11) * kDK + c) * kS + (row & 2047)] = f2bf(v);
        }
      }
    }
  }
}

// output projection: fp32 + bias straight to d_out
__global__ __launch_bounds__(256) void gemm_out(const ushort_t* __restrict__ A,
    const ushort_t* __restrict__ Wt, const float* __restrict__ bias,
    float* __restrict__ C) {
  f32x4 acc[4][4] = {};
  int row0 = blockIdx.y * 128, col0 = blockIdx.x * 128;
  gemm128(A, kDM, Wt, kDM, kDM, row0, col0, acc);
  int lane = threadIdx.x & 63, wave = threadIdx.x >> 6;
  int wr = wave >> 1, wc = wave & 1, lr = lane & 15, lg = lane >> 4;
  #pragma unroll
  for (int i = 0; i < 4; i++) {
    #pragma unroll
    for (int j = 0; j < 4; j++) {
      int col = col0 + wc * 64 + j * 16 + lr;
      float bv = bias[col];
      #pragma unroll
      for (int rr = 0; rr < 4; rr++) {
        int row = row0 + wr * 64 + i * 16 + lg * 4 + rr;
        C[(long)row * kDM + col] = acc[i][j][rr] + bv;
      }
    }
  }
}

// ---------------- flash attention v2: S^T + in-register P (16x16x16 PV) ----------------
// grid (S/128, B*NH), 4 waves 2x2: wr splits q (2x64), wc splits keys (2x64).
// QK: sacc = mfma_x32(A=K, B=Q) -> S^T frags (q=lane&15 -> lane-local softmax).
// P^T converts in-register to 16x16x16 B-frags (k=(lane>>4)*4+j matches C-layout).
// PV: accO(O^T)[d][q] partial over wave's keys; wc-pair combined via LDS at end.
__global__ __launch_bounds__(256, 2) void flash_attn(
    const ushort_t* __restrict__ Qb, const ushort_t* __restrict__ Kb,
    const ushort_t* __restrict__ Vt, ushort_t* __restrict__ Ob) {
  __shared__ __align__(16) unsigned char smem[65536];
  ushort_t* sK = (ushort_t*)smem;             // 32KB: frags f=tt*4+kk (x32 A-layout)
  ushort_t* sV = (ushort_t*)(smem + 32768);   // 32KB: blocks beta=t*4+ss (key-contig)

  const int tid = threadIdx.x;
  const int L = tid & 63, wave = tid >> 6;
  const int wr = wave >> 1, wc = wave & 1;
  const int lr = L & 15, lg = L >> 4;
  const int bh = blockIdx.y, b = bh >> 4, h = bh & 15;
  const int q0 = blockIdx.x * 128;

  const ushort_t* Kg = Kb + (long)b * kS * kDK;
  const ushort_t* Vg = Vt + (long)b * kDK * kS;
  const ushort_t* Qg = Qb + ((long)b * kS + q0 + wr * 64) * kDM + h * kDK;

  f32x4 accO[8][4] = {};
  float lsum[4] = {};

  for (int j = 0; j < 16; j++) {
    __syncthreads();
    #pragma unroll
    for (int s = 0; s < 8; s++) {
      int c = tid + s * 256;
      int f = c >> 6, cl = c & 63;
      int clr = cl & 15, clg = cl >> 4;
      gload16(Kg + (long)(j * 128 + (f >> 2) * 16 + clr) * kDK + (f & 3) * 32 + clg * 8,
              (void*)(sK + c * 8));
      gload16(Vg + (long)((f >> 2) * 16 + clr) * kS + j * 128 + (f & 3) * 32 + clg * 8,
              (void*)(sV + c * 8));
    }
    __syncthreads();

    // QK -> S^T
    f32x4 sacc[4][4] = {};
    #pragma unroll
    for (int kk = 0; kk < 4; kk++) {
      bf16x8 qf[4];
      #pragma unroll
      for (int i = 0; i < 4; i++)
        qf[i] = *(const bf16x8*)(Qg + (long)(i * 16 + lr) * kDM + kk * 32 + lg * 8);
      #pragma unroll
      for (int s = 0; s < 4; s++) {
        bf16x8 kf = *(const bf16x8*)(sK + ((wc * 4 + s) * 4 + kk) * 512 + L * 8);
        #pragma unroll
        for (int i = 0; i < 4; i++)
          sacc[s][i] = __builtin_amdgcn_mfma_f32_16x16x32_bf16(kf, qf[i], sacc[s][i], 0, 0, 0);
      }
    }

    // P^T = exp(scale*S^T), packed directly into 16x16x16 B-frags
    s16x4 pf[4][4];
    #pragma unroll
    for (int s = 0; s < 4; s++)
      #pragma unroll
      for (int i = 0; i < 4; i++)
        #pragma unroll
        for (int r = 0; r < 4; r++) {
          float p = __expf(sacc[s][i][r] * 0.08838834764831845f);
          lsum[i] += p;
          pf[s][i][r] = (short)f2bf(p);
        }

    // PV via 16x16x16 mfma: accO[t][i] += Vt-frag(t, key-sub s) x pf[s][i]
    #pragma unroll
    for (int s = 0; s < 4; s++) {
      int cl2 = ((s & 1) * 2 + (lg >> 1)) * 16 + lr;
      int sub = (lg & 1) * 8;
      #pragma unroll
      for (int t = 0; t < 8; t++) {
        s16x4 vf = *(const s16x4*)((const unsigned char*)sV +
                     (t * 4 + wc * 2 + (s >> 1)) * 1024 + cl2 * 16 + sub);
        #pragma unroll
        for (int i = 0; i < 4; i++)
          accO[t][i] = __builtin_amdgcn_mfma_f32_16x16x16bf16_1k(vf, pf[s][i], accO[t][i], 0, 0, 0);
      }
    }
  }

  // softmax denominators: reduce over key-lane-groups, then wc-partner
  #pragma unroll
  for (int i = 0; i < 4; i++) {
    lsum[i] += __shfl_xor(lsum[i], 16);
    lsum[i] += __shfl_xor(lsum[i], 32);
  }
  __syncthreads();
  float* lbuf = (float*)smem;
  if (lg == 0)
    #pragma unroll
    for (int i = 0; i < 4; i++)
      lbuf[(wr * 2 + wc) * 64 + i * 16 + lr] = lsum[i];
  __syncthreads();
  float inv[4];
  #pragma unroll
  for (int i = 0; i < 4; i++)
    inv[i] = 1.0f / (lsum[i] + lbuf[(wr * 2 + (wc ^ 1)) * 64 + i * 16 + lr]);

  // combine wc-pair partial O^T: dump partner-owned d-half, read own half
  __syncthreads();
  #pragma unroll
  for (int tl = 0; tl < 4; tl++)
    #pragma unroll
    for (int i = 0; i < 4; i++)
      *(f32x4*)(smem + wave * 16384 + ((tl * 4 + i) * 64 + L) * 16)
          = accO[(wc ^ 1) * 4 + tl][i];
  __syncthreads();
  const int pw = wr * 2 + (wc ^ 1);
  ushort_t* Og = Ob + ((long)b * kS + q0 + wr * 64) * kDM + h * kDK;
  #pragma unroll
  for (int tl = 0; tl < 4; tl++) {
    int t = wc * 4 + tl;
    #pragma unroll
    for (int i = 0; i < 4; i++) {
      f32x4 part = *(const f32x4*)(smem + pw * 16384 + ((tl * 4 + i) * 64 + L) * 16);
      #pragma unroll
      for (int r = 0; r < 4; r++) {
        float v = (accO[t][i][r] + part[r]) * inv[i];
        Og[(long)(i * 16 + lr) * kDM + t * 16 + lg * 4 + r] = f2bf(v);
      }
    }
  }
}

extern "C" void kernel_launch(void* const* d_in, const int* in_sizes, int n_in,
                              void* d_out, int out_size, void* d_ws, size_t ws_size,
                              hipStream_t stream) {
  (void)in_sizes; (void)n_in; (void)out_size; (void)ws_size;
  const float* x   = (const float*)d_in[0];
  const float* W_q = (const float*)d_in[1];
  const float* b_q = (const float*)d_in[2];
  const float* W_k = (const float*)d_in[3];
  const float* b_k = (const float*)d_in[4];
  const float* W_v = (const float*)d_in[5];
  const float* b_v = (const float*)d_in[6];
  const float* W_o = (const float*)d_in[7];
  const float* b_o = (const float*)d_in[8];

  float* out = (float*)d_out;
  float* Kc  = out + (long)kB * kS * kDM;
  float* Vc  = Kc  + (long)kB * kS * kDK;

  char* w = (char*)d_ws;
  ushort_t* x_bf   = (ushort_t*)w;  w += 16777216;             // [4096, 2048]
  ushort_t* Wall_t = (ushort_t*)w;  w += (size_t)kNQKV*kDM*2;  // [2304, 2048]
  ushort_t* Wo_t   = (ushort_t*)w;  w += 8388608;              // [2048, 2048]
  ushort_t* Q_bf   = (ushort_t*)w;  w += 16777216;             // [4096, 2048]
  ushort_t* K_bf   = (ushort_t*)w;  w += 1048576;              // [B, S, DK]
  ushort_t* Vt_bf  = (ushort_t*)w;  w += 1048576;              // [B, DK, S]
  ushort_t* O_bf   = (ushort_t*)w;  w += 16777216;             // [4096, 2048]

  dim3 blk(256);
  dim3 tblk(32, 8);

  cast_f32_bf16<<<dim3(8192), blk, 0, stream>>>(x, x_bf, (long)kB * kS * kDM);
  transpose_cast<<<dim3(64, 64), tblk, 0, stream>>>(W_q, Wall_t, kDM, kDM);
  transpose_cast<<<dim3(4, 64),  tblk, 0, stream>>>(W_k, Wall_t + (long)kDM * kDM, kDM, kDK);
  transpose_cast<<<dim3(4, 64),  tblk, 0, stream>>>(W_v, Wall_t + (long)(kDM + kDK) * kDM, kDM, kDK);
  transpose_cast<<<dim3(64, 64), tblk, 0, stream>>>(W_o, Wo_t, kDM, kDM);

  gemm_qkv<<<dim3(kNQKV / 128, kB * kS / 128), blk, 0, stream>>>(
      x_bf, Wall_t, b_q, b_k, b_v, Q_bf, Kc, K_bf, Vc, Vt_bf);

  flash_attn<<<dim3(kS / 128, kB * kNH), blk, 0, stream>>>(Q_bf, K_bf, Vt_bf, O_bf);

  gemm_out<<<dim3(kDM / 128, kB * kS / 128), blk, 0, stream>>>(O_bf, Wo_t, b_o, out);
}

// Round 5
// 476.557 us; speedup vs baseline: 2.9651x; 2.9651x over previous
//
#include <hip/hip_runtime.h>
#include <cstdint>

typedef __bf16 bf16x8 __attribute__((ext_vector_type(8)));
typedef short s16x4 __attribute__((ext_vector_type(4)));
typedef float f32x4 __attribute__((ext_vector_type(4)));
typedef unsigned short ushort_t;

constexpr int kS  = 2048;
constexpr int kDM = 2048;
constexpr int kDK = 128;
constexpr int kNH = 16;
constexpr int kB  = 2;
constexpr int kNQKV = kDM + 2 * kDK;   // 2304 fused QKV output columns

__device__ __forceinline__ unsigned short f2bf(float f) {
  union { float f; unsigned u; } v; v.f = f;
  unsigned u = v.u;
  u += 0x7fffu + ((u >> 16) & 1u);
  return (unsigned short)(u >> 16);
}

// async global->LDS, 16B per lane (dest = wave-uniform base + lane*16)
__device__ __forceinline__ void gload16(const void* g, void* l) {
  __builtin_amdgcn_global_load_lds(
      (const __attribute__((address_space(1))) void*)g,
      (__attribute__((address_space(3))) void*)l, 16, 0, 0);
}

// ---------------- fp32 -> bf16 cast ----------------
__global__ __launch_bounds__(256) void cast_f32_bf16(const float* __restrict__ in,
                                                     ushort_t* __restrict__ out, long n) {
  long i = ((long)blockIdx.x * 256 + threadIdx.x) * 4;
  if (i >= n) return;
  float4 f = *reinterpret_cast<const float4*>(in + i);
  ushort4 o;
  o.x = f2bf(f.x); o.y = f2bf(f.y); o.z = f2bf(f.z); o.w = f2bf(f.w);
  *reinterpret_cast<ushort4*>(out + i) = o;
}

// ---------------- transpose + cast: fp32 [R x C] -> bf16 [C x R] ----------------
__global__ __launch_bounds__(256) void transpose_cast(const float* __restrict__ in,
                                                      ushort_t* __restrict__ out,
                                                      int R, int C) {
  __shared__ float tile[32][33];
  int c = blockIdx.x * 32 + threadIdx.x;
  int r0 = blockIdx.y * 32;
  #pragma unroll
  for (int i = threadIdx.y; i < 32; i += 8)
    tile[i][threadIdx.x] = in[(long)(r0 + i) * C + c];
  __syncthreads();
  int oc  = r0 + threadIdx.x;
  int or0 = blockIdx.x * 32;
  #pragma unroll
  for (int i = threadIdx.y; i < 32; i += 8)
    out[(long)(or0 + i) * R + oc] = f2bf(tile[threadIdx.x][i]);
}

// ---------------- 128x128 GEMM core (row-major LDS, 64B-contig staging) ----------------
__device__ __forceinline__ void gemm128(const ushort_t* __restrict__ A, int lda,
                                        const ushort_t* __restrict__ Bt, int ldb,
                                        int K, int row0, int col0,
                                        f32x4 (&acc)[4][4]) {
  __shared__ __align__(16) ushort_t sA[128 * 32];
  __shared__ __align__(16) ushort_t sB[128 * 32];
  int t = threadIdx.x;
  int r = t >> 2, c4 = t & 3;
  const ushort_t* gA0 = A  + (long)(row0 + r)      * lda + c4 * 8;
  const ushort_t* gA1 = A  + (long)(row0 + r + 64) * lda + c4 * 8;
  const ushort_t* gB0 = Bt + (long)(col0 + r)      * ldb + c4 * 8;
  const ushort_t* gB1 = Bt + (long)(col0 + r + 64) * ldb + c4 * 8;
  int lane = t & 63, wave = t >> 6;
  int wr = wave >> 1, wc = wave & 1;
  int lr = lane & 15, lg = lane >> 4;
  int aoff = (wr * 64 + lr) * 32 + lg * 8;
  int boff = (wc * 64 + lr) * 32 + lg * 8;

  for (int kk = 0; kk < K; kk += 32) {
    gload16(gA0 + kk, (void*)(sA + t * 8));
    gload16(gA1 + kk, (void*)(sA + 2048 + t * 8));
    gload16(gB0 + kk, (void*)(sB + t * 8));
    gload16(gB1 + kk, (void*)(sB + 2048 + t * 8));
    __syncthreads();
    bf16x8 af[4], bg[4];
    #pragma unroll
    for (int i = 0; i < 4; i++) af[i] = *(const bf16x8*)(sA + aoff + i * 16 * 32);
    #pragma unroll
    for (int j = 0; j < 4; j++) bg[j] = *(const bf16x8*)(sB + boff + j * 16 * 32);
    #pragma unroll
    for (int i = 0; i < 4; i++)
      #pragma unroll
      for (int j = 0; j < 4; j++)
        acc[i][j] = __builtin_amdgcn_mfma_f32_16x16x32_bf16(af[i], bg[j], acc[i][j], 0, 0, 0);
    __syncthreads();
  }
}

// fused QKV projection (+ fused V^T production)
__global__ __launch_bounds__(256) void gemm_qkv(const ushort_t* __restrict__ x,
    const ushort_t* __restrict__ Wt, const float* __restrict__ bq,
    const float* __restrict__ bk, const float* __restrict__ bv,
    ushort_t* __restrict__ Qb, float* __restrict__ Kc,
    ushort_t* __restrict__ Kb, float* __restrict__ Vc, ushort_t* __restrict__ Vtb) {
  f32x4 acc[4][4] = {};
  int row0 = blockIdx.y * 128, col0 = blockIdx.x * 128;
  gemm128(x, kDM, Wt, kDM, kDM, row0, col0, acc);
  int lane = threadIdx.x & 63, wave = threadIdx.x >> 6;
  int wr = wave >> 1, wc = wave & 1, lr = lane & 15, lg = lane >> 4;
  #pragma unroll
  for (int i = 0; i < 4; i++) {
    #pragma unroll
    for (int j = 0; j < 4; j++) {
      int col = col0 + wc * 64 + j * 16 + lr;
      float bias = (col < kDM) ? bq[col]
                 : (col < kDM + kDK) ? bk[col - kDM] : bv[col - kDM - kDK];
      #pragma unroll
      for (int rr = 0; rr < 4; rr++) {
        int row = row0 + wr * 64 + i * 16 + lg * 4 + rr;
        float v = acc[i][j][rr] + bias;
        if (col < kDM) {
          Qb[(long)row * kDM + col] = f2bf(v);
        } else if (col < kDM + kDK) {
          int c = col - kDM;
          Kc[(long)row * kDK + c] = v;
          Kb[(long)row * kDK + c] = f2bf(v);
        } else {
          int c = col - kDM - kDK;
          Vc[(long)row * kDK + c] = v;
          Vtb[((long)(row >> 11) * kDK + c) * kS + (row & 2047)] = f2bf(v);
        }
      }
    }
  }
}

// output projection: fp32 + bias straight to d_out
__global__ __launch_bounds__(256) void gemm_out(const ushort_t* __restrict__ A,
    const ushort_t* __restrict__ Wt, const float* __restrict__ bias,
    float* __restrict__ C) {
  f32x4 acc[4][4] = {};
  int row0 = blockIdx.y * 128, col0 = blockIdx.x * 128;
  gemm128(A, kDM, Wt, kDM, kDM, row0, col0, acc);
  int lane = threadIdx.x & 63, wave = threadIdx.x >> 6;
  int wr = wave >> 1, wc = wave & 1, lr = lane & 15, lg = lane >> 4;
  #pragma unroll
  for (int i = 0; i < 4; i++) {
    #pragma unroll
    for (int j = 0; j < 4; j++) {
      int col = col0 + wc * 64 + j * 16 + lr;
      float bv = bias[col];
      #pragma unroll
      for (int rr = 0; rr < 4; rr++) {
        int row = row0 + wr * 64 + i * 16 + lg * 4 + rr;
        C[(long)row * kDM + col] = acc[i][j][rr] + bv;
      }
    }
  }
}

// ---------------- flash attention v2.1: S^T + in-register P (16x16x16 PV) ----------------
// Identical algorithm to R3, but the wc-dependent epilogue uses wave-uniform
// branches with COMPILE-TIME register indices so accO stays in VGPRs
// (R3's accO[(wc^1)*4+tl] dynamic indexing demoted accO to scratch -> 6.5GB HBM).
__global__ __launch_bounds__(256, 2) void flash_attn(
    const ushort_t* __restrict__ Qb, const ushort_t* __restrict__ Kb,
    const ushort_t* __restrict__ Vt, ushort_t* __restrict__ Ob) {
  __shared__ __align__(16) unsigned char smem[65536];
  ushort_t* sK = (ushort_t*)smem;             // 32KB: frags f=keytile*4+kk (x32 A-layout)
  ushort_t* sV = (ushort_t*)(smem + 32768);   // 32KB: blocks beta=dtile*4+key32 (key-contig)

  const int tid = threadIdx.x;
  const int L = tid & 63, wave = tid >> 6;
  const int wr = wave >> 1, wc = wave & 1;
  const int lr = L & 15, lg = L >> 4;
  const int bh = blockIdx.y, b = bh >> 4, h = bh & 15;
  const int q0 = blockIdx.x * 128;

  const ushort_t* Kg = Kb + (long)b * kS * kDK;
  const ushort_t* Vg = Vt + (long)b * kDK * kS;
  const ushort_t* Qg = Qb + ((long)b * kS + q0 + wr * 64) * kDM + h * kDK;

  f32x4 accO[8][4] = {};
  float lsum[4] = {};

  for (int j = 0; j < 16; j++) {
    __syncthreads();
    #pragma unroll
    for (int s = 0; s < 8; s++) {
      int c = tid + s * 256;
      int f = c >> 6, cl = c & 63;
      int clr = cl & 15, clg = cl >> 4;
      gload16(Kg + (long)(j * 128 + (f >> 2) * 16 + clr) * kDK + (f & 3) * 32 + clg * 8,
              (void*)(sK + c * 8));
      gload16(Vg + (long)((f >> 2) * 16 + clr) * kS + j * 128 + (f & 3) * 32 + clg * 8,
              (void*)(sV + c * 8));
    }
    __syncthreads();

    // QK -> S^T
    f32x4 sacc[4][4] = {};
    #pragma unroll
    for (int kk = 0; kk < 4; kk++) {
      bf16x8 qf[4];
      #pragma unroll
      for (int i = 0; i < 4; i++)
        qf[i] = *(const bf16x8*)(Qg + (long)(i * 16 + lr) * kDM + kk * 32 + lg * 8);
      #pragma unroll
      for (int s = 0; s < 4; s++) {
        bf16x8 kf = *(const bf16x8*)(sK + ((wc * 4 + s) * 4 + kk) * 512 + L * 8);
        #pragma unroll
        for (int i = 0; i < 4; i++)
          sacc[s][i] = __builtin_amdgcn_mfma_f32_16x16x32_bf16(kf, qf[i], sacc[s][i], 0, 0, 0);
      }
    }

    // P^T = exp(scale*S^T), packed directly into 16x16x16 B-frags
    s16x4 pf[4][4];
    #pragma unroll
    for (int s = 0; s < 4; s++)
      #pragma unroll
      for (int i = 0; i < 4; i++)
        #pragma unroll
        for (int r = 0; r < 4; r++) {
          float p = __expf(sacc[s][i][r] * 0.08838834764831845f);
          lsum[i] += p;
          pf[s][i][r] = (short)f2bf(p);
        }

    // PV via 16x16x16 mfma: accO[t][i] += Vt-frag(t, key-sub s) x pf[s][i]
    #pragma unroll
    for (int s = 0; s < 4; s++) {
      int cl2 = ((s & 1) * 2 + (lg >> 1)) * 16 + lr;
      int sub = (lg & 1) * 8;
      #pragma unroll
      for (int t = 0; t < 8; t++) {
        s16x4 vf = *(const s16x4*)((const unsigned char*)sV +
                     (t * 4 + wc * 2 + (s >> 1)) * 1024 + cl2 * 16 + sub);
        #pragma unroll
        for (int i = 0; i < 4; i++)
          accO[t][i] = __builtin_amdgcn_mfma_f32_16x16x16bf16_1k(vf, pf[s][i], accO[t][i], 0, 0, 0);
      }
    }
  }

  // softmax denominators: reduce over key-lane-groups, then wc-partner
  #pragma unroll
  for (int i = 0; i < 4; i++) {
    lsum[i] += __shfl_xor(lsum[i], 16);
    lsum[i] += __shfl_xor(lsum[i], 32);
  }
  __syncthreads();
  float* lbuf = (float*)smem;
  if (lg == 0)
    #pragma unroll
    for (int i = 0; i < 4; i++)
      lbuf[(wr * 2 + wc) * 64 + i * 16 + lr] = lsum[i];
  __syncthreads();
  float inv[4];
  #pragma unroll
  for (int i = 0; i < 4; i++)
    inv[i] = 1.0f / (lsum[i] + lbuf[(wr * 2 + (wc ^ 1)) * 64 + i * 16 + lr]);

  // combine wc-pair partial O^T. Wave-uniform branch, STATIC accO indices.
  __syncthreads();
  if (wc == 0) {
    #pragma unroll
    for (int tl = 0; tl < 4; tl++)
      #pragma unroll
      for (int i = 0; i < 4; i++)
        *(f32x4*)(smem + wave * 16384 + ((tl * 4 + i) * 64 + L) * 16) = accO[4 + tl][i];
  } else {
    #pragma unroll
    for (int tl = 0; tl < 4; tl++)
      #pragma unroll
      for (int i = 0; i < 4; i++)
        *(f32x4*)(smem + wave * 16384 + ((tl * 4 + i) * 64 + L) * 16) = accO[tl][i];
  }
  __syncthreads();
  const int pw = wr * 2 + (wc ^ 1);
  ushort_t* Og = Ob + ((long)b * kS + q0 + wr * 64) * kDM + h * kDK;
  if (wc == 0) {
    #pragma unroll
    for (int tl = 0; tl < 4; tl++)
      #pragma unroll
      for (int i = 0; i < 4; i++) {
        f32x4 part = *(const f32x4*)(smem + pw * 16384 + ((tl * 4 + i) * 64 + L) * 16);
        #pragma unroll
        for (int r = 0; r < 4; r++) {
          float v = (accO[tl][i][r] + part[r]) * inv[i];
          Og[(long)(i * 16 + lr) * kDM + tl * 16 + lg * 4 + r] = f2bf(v);
        }
      }
  } else {
    #pragma unroll
    for (int tl = 0; tl < 4; tl++)
      #pragma unroll
      for (int i = 0; i < 4; i++) {
        f32x4 part = *(const f32x4*)(smem + pw * 16384 + ((tl * 4 + i) * 64 + L) * 16);
        #pragma unroll
        for (int r = 0; r < 4; r++) {
          float v = (accO[4 + tl][i][r] + part[r]) * inv[i];
          Og[(long)(i * 16 + lr) * kDM + (4 + tl) * 16 + lg * 4 + r] = f2bf(v);
        }
      }
  }
}

extern "C" void kernel_launch(void* const* d_in, const int* in_sizes, int n_in,
                              void* d_out, int out_size, void* d_ws, size_t ws_size,
                              hipStream_t stream) {
  (void)in_sizes; (void)n_in; (void)out_size; (void)ws_size;
  const float* x   = (const float*)d_in[0];
  const float* W_q = (const float*)d_in[1];
  const float* b_q = (const float*)d_in[2];
  const float* W_k = (const float*)d_in[3];
  const float* b_k = (const float*)d_in[4];
  const float* W_v = (const float*)d_in[5];
  const float* b_v = (const float*)d_in[6];
  const float* W_o = (const float*)d_in[7];
  const float* b_o = (const float*)d_in[8];

  float* out = (float*)d_out;
  float* Kc  = out + (long)kB * kS * kDM;
  float* Vc  = Kc  + (long)kB * kS * kDK;

  char* w = (char*)d_ws;
  ushort_t* x_bf   = (ushort_t*)w;  w += 16777216;             // [4096, 2048]
  ushort_t* Wall_t = (ushort_t*)w;  w += (size_t)kNQKV*kDM*2;  // [2304, 2048]
  ushort_t* Wo_t   = (ushort_t*)w;  w += 8388608;              // [2048, 2048]
  ushort_t* Q_bf   = (ushort_t*)w;  w += 16777216;             // [4096, 2048]
  ushort_t* K_bf   = (ushort_t*)w;  w += 1048576;              // [B, S, DK]
  ushort_t* Vt_bf  = (ushort_t*)w;  w += 1048576;              // [B, DK, S]
  ushort_t* O_bf   = (ushort_t*)w;  w += 16777216;             // [4096, 2048]

  dim3 blk(256);
  dim3 tblk(32, 8);

  cast_f32_bf16<<<dim3(8192), blk, 0, stream>>>(x, x_bf, (long)kB * kS * kDM);
  transpose_cast<<<dim3(64, 64), tblk, 0, stream>>>(W_q, Wall_t, kDM, kDM);
  transpose_cast<<<dim3(4, 64),  tblk, 0, stream>>>(W_k, Wall_t + (long)kDM * kDM, kDM, kDK);
  transpose_cast<<<dim3(4, 64),  tblk, 0, stream>>>(W_v, Wall_t + (long)(kDM + kDK) * kDM, kDM, kDK);
  transpose_cast<<<dim3(64, 64), tblk, 0, stream>>>(W_o, Wo_t, kDM, kDM);

  gemm_qkv<<<dim3(kNQKV / 128, kB * kS / 128), blk, 0, stream>>>(
      x_bf, Wall_t, b_q, b_k, b_v, Q_bf, Kc, K_bf, Vc, Vt_bf);

  flash_attn<<<dim3(kS / 128, kB * kNH), blk, 0, stream>>>(Q_bf, K_bf, Vt_bf, O_bf);

  gemm_out<<<dim3(kDM / 128, kB * kS / 128), blk, 0, stream>>>(O_bf, Wo_t, b_o, out);
}

// Round 6
// 339.556 us; speedup vs baseline: 4.1615x; 1.4035x over previous
//
#include <hip/hip_runtime.h>
#include <cstdint>

typedef __bf16 bf16x8 __attribute__((ext_vector_type(8)));
typedef short s16x4 __attribute__((ext_vector_type(4)));
typedef float f32x4 __attribute__((ext_vector_type(4)));
typedef unsigned short ushort_t;

constexpr int kS  = 2048;
constexpr int kDM = 2048;
constexpr int kDK = 128;
constexpr int kNH = 16;
constexpr int kB  = 2;
constexpr int kNQKV = kDM + 2 * kDK;   // 2304 fused QKV output columns

__device__ __forceinline__ unsigned short f2bf(float f) {
  union { float f; unsigned u; } v; v.f = f;
  unsigned u = v.u;
  u += 0x7fffu + ((u >> 16) & 1u);
  return (unsigned short)(u >> 16);
}

// async global->LDS, 16B per lane (dest = wave-uniform base + lane*16)
__device__ __forceinline__ void gload16(const void* g, void* l) {
  __builtin_amdgcn_global_load_lds(
      (const __attribute__((address_space(1))) void*)g,
      (__attribute__((address_space(3))) void*)l, 16, 0, 0);
}

// ---------------- fp32 -> bf16 cast ----------------
__global__ __launch_bounds__(256) void cast_f32_bf16(const float* __restrict__ in,
                                                     ushort_t* __restrict__ out, long n) {
  long i = ((long)blockIdx.x * 256 + threadIdx.x) * 4;
  if (i >= n) return;
  float4 f = *reinterpret_cast<const float4*>(in + i);
  ushort4 o;
  o.x = f2bf(f.x); o.y = f2bf(f.y); o.z = f2bf(f.z); o.w = f2bf(f.w);
  *reinterpret_cast<ushort4*>(out + i) = o;
}

// ---------------- transpose + cast: fp32 [R x C] -> bf16 [C x R] ----------------
__global__ __launch_bounds__(256) void transpose_cast(const float* __restrict__ in,
                                                      ushort_t* __restrict__ out,
                                                      int R, int C) {
  __shared__ float tile[32][33];
  int c = blockIdx.x * 32 + threadIdx.x;
  int r0 = blockIdx.y * 32;
  #pragma unroll
  for (int i = threadIdx.y; i < 32; i += 8)
    tile[i][threadIdx.x] = in[(long)(r0 + i) * C + c];
  __syncthreads();
  int oc  = r0 + threadIdx.x;
  int or0 = blockIdx.x * 32;
  #pragma unroll
  for (int i = threadIdx.y; i < 32; i += 8)
    out[(long)(or0 + i) * R + oc] = f2bf(tile[threadIdx.x][i]);
}

// ---------------- 128x128 GEMM core (row-major LDS, 64B-contig staging) ----------------
__device__ __forceinline__ void gemm128(const ushort_t* __restrict__ A, int lda,
                                        const ushort_t* __restrict__ Bt, int ldb,
                                        int K, int row0, int col0,
                                        f32x4 (&acc)[4][4]) {
  __shared__ __align__(16) ushort_t sA[128 * 32];
  __shared__ __align__(16) ushort_t sB[128 * 32];
  int t = threadIdx.x;
  int r = t >> 2, c4 = t & 3;
  const ushort_t* gA0 = A  + (long)(row0 + r)      * lda + c4 * 8;
  const ushort_t* gA1 = A  + (long)(row0 + r + 64) * lda + c4 * 8;
  const ushort_t* gB0 = Bt + (long)(col0 + r)      * ldb + c4 * 8;
  const ushort_t* gB1 = Bt + (long)(col0 + r + 64) * ldb + c4 * 8;
  int lane = t & 63, wave = t >> 6;
  int wr = wave >> 1, wc = wave & 1;
  int lr = lane & 15, lg = lane >> 4;
  int aoff = (wr * 64 + lr) * 32 + lg * 8;
  int boff = (wc * 64 + lr) * 32 + lg * 8;

  for (int kk = 0; kk < K; kk += 32) {
    gload16(gA0 + kk, (void*)(sA + t * 8));
    gload16(gA1 + kk, (void*)(sA + 2048 + t * 8));
    gload16(gB0 + kk, (void*)(sB + t * 8));
    gload16(gB1 + kk, (void*)(sB + 2048 + t * 8));
    __syncthreads();
    bf16x8 af[4], bg[4];
    #pragma unroll
    for (int i = 0; i < 4; i++) af[i] = *(const bf16x8*)(sA + aoff + i * 16 * 32);
    #pragma unroll
    for (int j = 0; j < 4; j++) bg[j] = *(const bf16x8*)(sB + boff + j * 16 * 32);
    #pragma unroll
    for (int i = 0; i < 4; i++)
      #pragma unroll
      for (int j = 0; j < 4; j++)
        acc[i][j] = __builtin_amdgcn_mfma_f32_16x16x32_bf16(af[i], bg[j], acc[i][j], 0, 0, 0);
    __syncthreads();
  }
}

// fused QKV projection (+ fused V^T production)
__global__ __launch_bounds__(256) void gemm_qkv(const ushort_t* __restrict__ x,
    const ushort_t* __restrict__ Wt, const float* __restrict__ bq,
    const float* __restrict__ bk, const float* __restrict__ bv,
    ushort_t* __restrict__ Qb, float* __restrict__ Kc,
    ushort_t* __restrict__ Kb, float* __restrict__ Vc, ushort_t* __restrict__ Vtb) {
  f32x4 acc[4][4] = {};
  int row0 = blockIdx.y * 128, col0 = blockIdx.x * 128;
  gemm128(x, kDM, Wt, kDM, kDM, row0, col0, acc);
  int lane = threadIdx.x & 63, wave = threadIdx.x >> 6;
  int wr = wave >> 1, wc = wave & 1, lr = lane & 15, lg = lane >> 4;
  #pragma unroll
  for (int i = 0; i < 4; i++) {
    #pragma unroll
    for (int j = 0; j < 4; j++) {
      int col = col0 + wc * 64 + j * 16 + lr;
      float bias = (col < kDM) ? bq[col]
                 : (col < kDM + kDK) ? bk[col - kDM] : bv[col - kDM - kDK];
      #pragma unroll
      for (int rr = 0; rr < 4; rr++) {
        int row = row0 + wr * 64 + i * 16 + lg * 4 + rr;
        float v = acc[i][j][rr] + bias;
        if (col < kDM) {
          Qb[(long)row * kDM + col] = f2bf(v);
        } else if (col < kDM + kDK) {
          int c = col - kDM;
          Kc[(long)row * kDK + c] = v;
          Kb[(long)row * kDK + c] = f2bf(v);
        } else {
          int c = col - kDM - kDK;
          Vc[(long)row * kDK + c] = v;
          Vtb[((long)(row >> 11) * kDK + c) * kS + (row & 2047)] = f2bf(v);
        }
      }
    }
  }
}

// output projection: fp32 + bias straight to d_out
__global__ __launch_bounds__(256) void gemm_out(const ushort_t* __restrict__ A,
    const ushort_t* __restrict__ Wt, const float* __restrict__ bias,
    float* __restrict__ C) {
  f32x4 acc[4][4] = {};
  int row0 = blockIdx.y * 128, col0 = blockIdx.x * 128;
  gemm128(A, kDM, Wt, kDM, kDM, row0, col0, acc);
  int lane = threadIdx.x & 63, wave = threadIdx.x >> 6;
  int wr = wave >> 1, wc = wave & 1, lr = lane & 15, lg = lane >> 4;
  #pragma unroll
  for (int i = 0; i < 4; i++) {
    #pragma unroll
    for (int j = 0; j < 4; j++) {
      int col = col0 + wc * 64 + j * 16 + lr;
      float bv = bias[col];
      #pragma unroll
      for (int rr = 0; rr < 4; rr++) {
        int row = row0 + wr * 64 + i * 16 + lg * 4 + rr;
        C[(long)row * kDM + col] = acc[i][j][rr] + bv;
      }
    }
  }
}

// ---------------- flash attention v3: q-split waves, no spill ----------------
// grid (S/128, B*NH). 4 waves: wave w owns q rows [w*32, w*32+32), ALL keys & d.
// Q frags loaded ONCE to registers. Per 128-key j-tile: stage K (frag-major,
// 32KB) + V^T (row-major stride 128, XOR-swizzled chunks, 32KB).
// QK: sacc = mfma_x32(A=K, B=Q) -> S^T frags (lane: q=lr, keys=lg*4+r).
// S^T C-frag IS the x16 B-frag of P (k=lg*4+j) -> in-register exp -> PV x16.
// Keys processed in 2 halves of 64 to bound live sacc/pf (32+16 regs).
__global__ __launch_bounds__(256, 2) void flash_attn(
    const ushort_t* __restrict__ Qb, const ushort_t* __restrict__ Kb,
    const ushort_t* __restrict__ Vt, ushort_t* __restrict__ Ob) {
  __shared__ __align__(16) ushort_t sK[128 * 128];  // 32KB frag-major x32-A frags
  __shared__ __align__(16) ushort_t sV[128 * 128];  // 32KB V^T rows, swizzled chunks

  const int tid = threadIdx.x;
  const int L = tid & 63, wave = tid >> 6;
  const int lr = L & 15, lg = L >> 4;
  const int bh = blockIdx.y, b = bh >> 4, h = bh & 15;
  const int q0 = blockIdx.x * 128;

  const ushort_t* Kg = Kb + (long)b * kS * kDK;
  const ushort_t* Vg = Vt + (long)b * kDK * kS;
  const ushort_t* Qg = Qb + ((long)b * kS + q0 + wave * 32) * kDM + h * kDK;

  // Q fragments: 2 q-tiles x 4 kk -> 32 VGPRs, loaded once
  bf16x8 qf[2][4];
  #pragma unroll
  for (int i = 0; i < 2; i++)
    #pragma unroll
    for (int kk = 0; kk < 4; kk++)
      qf[i][kk] = *(const bf16x8*)(Qg + (long)(i * 16 + lr) * kDM + kk * 32 + lg * 8);

  f32x4 accO[8][2] = {};   // O^T: 8 d-tiles x 2 q-tiles (64 regs)
  float lsum[2] = {};

  for (int j = 0; j < 16; j++) {
    __syncthreads();
    #pragma unroll
    for (int s = 0; s < 8; s++) {
      int c = tid + s * 256;
      // K: frag f=keytile*4+kkblk (1KB each): chunk c: f=c>>6, slot cl=c&63
      int f = c >> 6, cl = c & 63;
      gload16(Kg + (long)(j * 128 + (f >> 2) * 16 + (cl & 15)) * kDK + (f & 3) * 32 + (cl >> 4) * 8,
              (void*)(sK + c * 8));
      // V^T: row d=c>>4, swizzled chunk kbL=c&15 <- global kb = kbL ^ (d&15)
      int d = c >> 4, kb = (c & 15) ^ (d & 15);
      gload16(Vg + (long)d * kS + j * 128 + kb * 8, (void*)(sV + c * 8));
    }
    __syncthreads();

    #pragma unroll
    for (int half = 0; half < 2; half++) {
      // QK -> S^T for 4 key-tiles
      f32x4 sacc[4][2] = {};
      #pragma unroll
      for (int kk = 0; kk < 4; kk++)
        #pragma unroll
        for (int s = 0; s < 4; s++) {
          bf16x8 kf = *(const bf16x8*)(sK + ((half * 4 + s) * 4 + kk) * 512 + L * 8);
          #pragma unroll
          for (int i = 0; i < 2; i++)
            sacc[s][i] = __builtin_amdgcn_mfma_f32_16x16x32_bf16(kf, qf[i][kk], sacc[s][i], 0, 0, 0);
        }

      // P^T = exp(scale*S^T): packed in-register into x16 B-frags
      s16x4 pf[4][2];
      #pragma unroll
      for (int s = 0; s < 4; s++)
        #pragma unroll
        for (int i = 0; i < 2; i++)
          #pragma unroll
          for (int r = 0; r < 4; r++) {
            float p = __expf(sacc[s][i][r] * 0.08838834764831845f);
            lsum[i] += p;
            pf[s][i][r] = (short)f2bf(p);
          }

      // PV x16: accO[t][i] += Vt-Afrag(t, keysub half*4+s) x pf[s][i]
      #pragma unroll
      for (int s = 0; s < 4; s++) {
        int ss = half * 4 + s;
        int kbL = (ss * 2 + (lg >> 1)) ^ lr;          // swizzled chunk
        int voff = lr * 128 + kbL * 8 + (lg & 1) * 4; // + t*16*128 per d-tile
        #pragma unroll
        for (int t = 0; t < 8; t++) {
          s16x4 vf = *(const s16x4*)(sV + t * 2048 + voff);
          #pragma unroll
          for (int i = 0; i < 2; i++)
            accO[t][i] = __builtin_amdgcn_mfma_f32_16x16x16bf16_1k(vf, pf[s][i], accO[t][i], 0, 0, 0);
        }
      }
    }
  }

  // softmax denominators: keys split across lg only -> shfl reduce
  float inv[2];
  #pragma unroll
  for (int i = 0; i < 2; i++) {
    float v = lsum[i];
    v += __shfl_xor(v, 16);
    v += __shfl_xor(v, 32);
    inv[i] = 1.0f / v;
  }

  // write O (transpose in addressing): lane holds O^T[d=t*16+lg*4+r][q=i*16+lr]
  ushort_t* Og = Ob + ((long)b * kS + q0 + wave * 32) * kDM + h * kDK;
  #pragma unroll
  for (int t = 0; t < 8; t++)
    #pragma unroll
    for (int i = 0; i < 2; i++) {
      ushort4 o;
      o.x = f2bf(accO[t][i][0] * inv[i]);
      o.y = f2bf(accO[t][i][1] * inv[i]);
      o.z = f2bf(accO[t][i][2] * inv[i]);
      o.w = f2bf(accO[t][i][3] * inv[i]);
      *(ushort4*)(Og + (long)(i * 16 + lr) * kDM + t * 16 + lg * 4) = o;
    }
}

extern "C" void kernel_launch(void* const* d_in, const int* in_sizes, int n_in,
                              void* d_out, int out_size, void* d_ws, size_t ws_size,
                              hipStream_t stream) {
  (void)in_sizes; (void)n_in; (void)out_size; (void)ws_size;
  const float* x   = (const float*)d_in[0];
  const float* W_q = (const float*)d_in[1];
  const float* b_q = (const float*)d_in[2];
  const float* W_k = (const float*)d_in[3];
  const float* b_k = (const float*)d_in[4];
  const float* W_v = (const float*)d_in[5];
  const float* b_v = (const float*)d_in[6];
  const float* W_o = (const float*)d_in[7];
  const float* b_o = (const float*)d_in[8];

  float* out = (float*)d_out;
  float* Kc  = out + (long)kB * kS * kDM;
  float* Vc  = Kc  + (long)kB * kS * kDK;

  char* w = (char*)d_ws;
  ushort_t* x_bf   = (ushort_t*)w;  w += 16777216;             // [4096, 2048]
  ushort_t* Wall_t = (ushort_t*)w;  w += (size_t)kNQKV*kDM*2;  // [2304, 2048]
  ushort_t* Wo_t   = (ushort_t*)w;  w += 8388608;              // [2048, 2048]
  ushort_t* Q_bf   = (ushort_t*)w;  w += 16777216;             // [4096, 2048]
  ushort_t* K_bf   = (ushort_t*)w;  w += 1048576;              // [B, S, DK]
  ushort_t* Vt_bf  = (ushort_t*)w;  w += 1048576;              // [B, DK, S]
  ushort_t* O_bf   = (ushort_t*)w;  w += 16777216;             // [4096, 2048]

  dim3 blk(256);
  dim3 tblk(32, 8);

  cast_f32_bf16<<<dim3(8192), blk, 0, stream>>>(x, x_bf, (long)kB * kS * kDM);
  transpose_cast<<<dim3(64, 64), tblk, 0, stream>>>(W_q, Wall_t, kDM, kDM);
  transpose_cast<<<dim3(4, 64),  tblk, 0, stream>>>(W_k, Wall_t + (long)kDM * kDM, kDM, kDK);
  transpose_cast<<<dim3(4, 64),  tblk, 0, stream>>>(W_v, Wall_t + (long)(kDM + kDK) * kDM, kDM, kDK);
  transpose_cast<<<dim3(64, 64), tblk, 0, stream>>>(W_o, Wo_t, kDM, kDM);

  gemm_qkv<<<dim3(kNQKV / 128, kB * kS / 128), blk, 0, stream>>>(
      x_bf, Wall_t, b_q, b_k, b_v, Q_bf, Kc, K_bf, Vc, Vt_bf);

  flash_attn<<<dim3(kS / 128, kB * kNH), blk, 0, stream>>>(Q_bf, K_bf, Vt_bf, O_bf);

  gemm_out<<<dim3(kDM / 128, kB * kS / 128), blk, 0, stream>>>(O_bf, Wo_t, b_o, out);
}